// Round 1
// baseline (649.295 us; speedup 1.0000x reference)
//
#include <hip/hip_runtime.h>
#include <cstdint>
#include <cstddef>

#define B_ 256
#define C_ 3
#define IW_ 3072
#define L_ 8
#define NN_ 7
#define FCIN_ 16384
#define OUTW_ 10

// ---------- repack conv1 weights: [512][3][3][3] -> [512][28] (27 taps + pad) ----------
__global__ void k_repack_w1(const float* __restrict__ w1, float* __restrict__ w1r) {
    int i = blockIdx.x * 256 + threadIdx.x;
    if (i >= 512 * 28) return;
    int o = i / 28, t = i % 28;
    w1r[i] = (t < 27) ? w1[o * 27 + t] : 0.f;
}

// ---------- repack conv2 weights: [l][oc][ic][3][3] -> [l][ot4][ic64][tap9][oc16] ----------
__global__ void k_repack_w2(const float* __restrict__ w2, float* __restrict__ w2r) {
    int i = blockIdx.x * 256 + threadIdx.x;
    if (i >= 294912) return;
    int o16 = i & 15;
    int t   = (i >> 4) % 9;
    int ic  = (i / 144) & 63;
    int ot  = (i / 9216) & 3;
    int l   = i / 36864;
    w2r[i] = w2[((size_t)((l * 64 + ot * 16 + o16) * 64 + ic)) * 9 + t];
}

// ---------- mixture: per-sample soft tree weights [B][8] ----------
__global__ __launch_bounds__(256) void k_mixture(const float* __restrict__ x, const float* __restrict__ nw,
                                                 const float* __restrict__ nb, float* __restrict__ mix) {
    __shared__ float red[4 * NN_];
    __shared__ float bes[NN_];
    int b = blockIdx.x, tid = threadIdx.x;
    const float* xb = x + (size_t)b * IW_;
    float p[NN_];
#pragma unroll
    for (int n = 0; n < NN_; ++n) p[n] = 0.f;
    for (int i = tid; i < IW_; i += 256) {
        float xv = xb[i];
#pragma unroll
        for (int n = 0; n < NN_; ++n) p[n] = fmaf(xv, nw[n * IW_ + i], p[n]);
    }
#pragma unroll
    for (int n = 0; n < NN_; ++n) {
        float v = p[n];
        for (int off = 32; off > 0; off >>= 1) v += __shfl_xor(v, off);
        if ((tid & 63) == 0) red[(tid >> 6) * NN_ + n] = v;
    }
    __syncthreads();
    if (tid < NN_) {
        float s = red[tid] + red[NN_ + tid] + red[2 * NN_ + tid] + red[3 * NN_ + tid] + nb[tid];
        bes[tid] = 1.f / (1.f + expf(-s));
    }
    __syncthreads();
    if (tid < L_) {
        int leaf = tid;
        float b0 = bes[0];
        float t0 = ((leaf >> 2) & 1) ? b0 : 1.f - b0;
        float b1v = bes[1 + ((leaf >> 2) & 1)];
        float t1 = ((leaf >> 1) & 1) ? b1v : 1.f - b1v;
        float b2v = bes[3 + ((leaf >> 1) & 3)];
        float t2 = (leaf & 1) ? b2v : 1.f - b2v;
        mix[b * L_ + leaf] = t0 * t1 * t2;
    }
}

// ---------- conv1 + bias + maxpool2x2 + relu -> y1 [bc][512][16][16] ----------
__global__ __launch_bounds__(256) void k_conv1(const float* __restrict__ x, const float* __restrict__ w1r,
                                               const float* __restrict__ cb1, float* __restrict__ y1, int boff) {
    __shared__ float xl[IW_];       // [3][32][32]
    __shared__ float wl[64 * 28];   // 64 ocs of this tile, 28 floats each
    int tid = threadIdx.x;
    int bl = blockIdx.x >> 3, ot = blockIdx.x & 7;
    int b = boff + bl;
    {
        const float4* xs = (const float4*)(x + (size_t)b * IW_);
        for (int i = tid; i < IW_ / 4; i += 256) ((float4*)xl)[i] = xs[i];
        const float4* wsrc = (const float4*)(w1r + ot * 1792);
        for (int i = tid; i < 1792 / 4; i += 256) ((float4*)wl)[i] = wsrc[i];
    }
    __syncthreads();
    int tx = tid & 15, ty = tid >> 4;   // pooled position
    float pch[3][4][4];
#pragma unroll
    for (int c = 0; c < 3; ++c)
#pragma unroll
        for (int r = 0; r < 4; ++r)
#pragma unroll
            for (int s = 0; s < 4; ++s) {
                int gr = 2 * ty - 1 + r, gc = 2 * tx - 1 + s;
                bool ok = ((unsigned)gr < 32u) && ((unsigned)gc < 32u);
                float v = xl[c * 1024 + (ok ? gr * 32 + gc : 0)];
                pch[c][r][s] = ok ? v : 0.f;
            }
    float* yout = y1 + ((size_t)bl * 512 + ot * 64) * 256 + ty * 16 + tx;
#pragma unroll 4
    for (int oc = 0; oc < 64; ++oc) {
        const float* wp = wl + oc * 28;
        float a0 = 0.f, a1 = 0.f, a2 = 0.f, a3 = 0.f;
#pragma unroll
        for (int c = 0; c < 3; ++c)
#pragma unroll
            for (int kh = 0; kh < 3; ++kh)
#pragma unroll
                for (int kw = 0; kw < 3; ++kw) {
                    float w = wp[c * 9 + kh * 3 + kw];
                    a0 = fmaf(w, pch[c][kh][kw], a0);
                    a1 = fmaf(w, pch[c][kh][kw + 1], a1);
                    a2 = fmaf(w, pch[c][kh + 1][kw], a2);
                    a3 = fmaf(w, pch[c][kh + 1][kw + 1], a3);
                }
        float v = fmaxf(fmaxf(a0, a1), fmaxf(a2, a3)) + cb1[ot * 64 + oc];
        v = fmaxf(v, 0.f);
        yout[(size_t)oc * 256] = v;
    }
}

// ---------- conv2 (grouped) + bias + relu + mixture-weighted leaf reduction -> out1 [bc][64][16][16] ----------
// block = (bl, octile of 16). 256 thr = 64 pos-tiles(2x2) x 4 oc-groups(4 oc).
// LDS y plane [16ic][18][20]: data rows 1..16, cols 0..15; borders zero -> halo reads hit zeros via linear addressing.
__global__ __launch_bounds__(256) void k_conv2(const float* __restrict__ y1, const float* __restrict__ w2r,
                                               const float* __restrict__ cb2, const float* __restrict__ mixw,
                                               float* __restrict__ out1, int boff) {
    __shared__ float ylds_s[16 * 360 + 4];
    __shared__ float wl[2304];      // [16ic][9tap][16oc]
    float* yl = ylds_s + 4;
    int tid = threadIdx.x;
    int bl = blockIdx.x >> 2, ot = blockIdx.x & 3;
    int bg = boff + bl;
    int ocg = tid >> 6;
    int pt = tid & 63;
    int tyy = pt >> 3, txx = pt & 7;

    for (int i = tid; i < 16 * 360 + 4; i += 256) ylds_s[i] = 0.f;  // zero borders (stay zero)

    float acc[4][4], oacc[4][4];
#pragma unroll
    for (int o = 0; o < 4; ++o)
#pragma unroll
        for (int p = 0; p < 4; ++p) { acc[o][p] = 0.f; oacc[o][p] = 0.f; }

    const int ocb = ot * 16 + ocg * 4;
    const int prow = 2 * tyy;
    const int pcol = 2 * txx - 1;

    for (int l = 0; l < L_; ++l) {
        for (int icc = 0; icc < 4; ++icc) {
            __syncthreads();
            const float* ys = y1 + ((size_t)bl * 512 + l * 64 + icc * 16) * 256;
#pragma unroll
            for (int it = 0; it < 4; ++it) {
                int lin = it * 256 + tid;
                float4 v = *(const float4*)(ys + (size_t)lin * 4);
                int ic = lin >> 6;
                int rem = (lin & 63) << 2;
                int r = rem >> 4, c = rem & 15;
                *(float4*)&yl[ic * 360 + (r + 1) * 20 + c] = v;
            }
            const float* wsrc = w2r + ((size_t)(l * 4 + ot) * 64 + icc * 16) * 144;
#pragma unroll
            for (int i = 0; i < 3; ++i) {
                int f4 = i * 256 + tid;
                if (f4 < 576) ((float4*)wl)[f4] = ((const float4*)wsrc)[f4];
            }
            __syncthreads();
#pragma unroll 2
            for (int ic = 0; ic < 16; ++ic) {
                const float* yp = yl + ic * 360 + prow * 20 + pcol;
                float pch[4][4];
#pragma unroll
                for (int r = 0; r < 4; ++r)
#pragma unroll
                    for (int cc = 0; cc < 4; ++cc)
                        pch[r][cc] = yp[r * 20 + cc];
                const float* wp = wl + ic * 144 + ocg * 4;
#pragma unroll
                for (int kh = 0; kh < 3; ++kh)
#pragma unroll
                    for (int kw = 0; kw < 3; ++kw) {
                        float4 wv = *(const float4*)(wp + (kh * 3 + kw) * 16);
                        float wa[4] = {wv.x, wv.y, wv.z, wv.w};
#pragma unroll
                        for (int o = 0; o < 4; ++o)
#pragma unroll
                            for (int dy = 0; dy < 2; ++dy)
#pragma unroll
                                for (int dx = 0; dx < 2; ++dx)
                                    acc[o][dy * 2 + dx] = fmaf(wa[o], pch[dy + kh][dx + kw], acc[o][dy * 2 + dx]);
                    }
            }
        }
        float4 bv = *(const float4*)(cb2 + l * 64 + ocb);
        float bb[4] = {bv.x, bv.y, bv.z, bv.w};
        float m = mixw[(size_t)bg * 8 + l];
#pragma unroll
        for (int o = 0; o < 4; ++o)
#pragma unroll
            for (int p = 0; p < 4; ++p) {
                float v = fmaxf(acc[o][p] + bb[o], 0.f);
                oacc[o][p] = fmaf(m, v, oacc[o][p]);
                acc[o][p] = 0.f;
            }
    }
#pragma unroll
    for (int o = 0; o < 4; ++o) {
        int oc = ocb + o;
#pragma unroll
        for (int dy = 0; dy < 2; ++dy) {
            float2 st;
            st.x = oacc[o][dy * 2];
            st.y = oacc[o][dy * 2 + 1];
            *(float2*)(out1 + (((size_t)bl * 64 + oc) * 16 + prow + dy) * 16 + 2 * txx) = st;
        }
    }
}

// ---------- fc: [bc][16384] @ [10][16384]^T + b ----------
__global__ __launch_bounds__(256) void k_fc(const float* __restrict__ out1, const float* __restrict__ fcw,
                                            const float* __restrict__ fcb, float* __restrict__ out, int boff) {
    __shared__ float red[4][OUTW_];
    int tid = threadIdx.x;
    int bl = blockIdx.x;
    const float4* flat = (const float4*)(out1 + (size_t)bl * FCIN_);
    float pj[OUTW_];
#pragma unroll
    for (int j = 0; j < OUTW_; ++j) pj[j] = 0.f;
    for (int i = tid; i < FCIN_ / 4; i += 256) {
        float4 v = flat[i];
#pragma unroll
        for (int j = 0; j < OUTW_; ++j) {
            float4 w = ((const float4*)(fcw + (size_t)j * FCIN_))[i];
            pj[j] += v.x * w.x + v.y * w.y + v.z * w.z + v.w * w.w;
        }
    }
#pragma unroll
    for (int j = 0; j < OUTW_; ++j) {
        float v = pj[j];
        for (int off = 32; off > 0; off >>= 1) v += __shfl_xor(v, off);
        if ((tid & 63) == 0) red[tid >> 6][j] = v;
    }
    __syncthreads();
    if (tid < OUTW_) {
        float s = red[0][tid] + red[1][tid] + red[2][tid] + red[3][tid] + fcb[tid];
        out[(size_t)(boff + bl) * OUTW_ + tid] = s;
    }
}

extern "C" void kernel_launch(void* const* d_in, const int* in_sizes, int n_in,
                              void* d_out, int out_size, void* d_ws, size_t ws_size,
                              hipStream_t stream) {
    const float* x   = (const float*)d_in[0];
    const float* nw  = (const float*)d_in[1];
    const float* nb  = (const float*)d_in[2];
    const float* w1  = (const float*)d_in[3];
    const float* cb1 = (const float*)d_in[4];
    const float* w2  = (const float*)d_in[5];
    const float* cb2 = (const float*)d_in[6];
    const float* fcw = (const float*)d_in[7];
    const float* fcb = (const float*)d_in[8];
    float* out = (float*)d_out;

    float* ws  = (float*)d_ws;
    float* mix = ws;                    // 2048 floats
    float* w1r = mix + 2048;            // 14336 floats
    float* w2r = w1r + 14336;           // 294912 floats
    float* dyn = w2r + 294912;

    // batch-chunk so y1+out1 scratch fits ws_size
    long wsf = (long)(ws_size / 4);
    long avail = wsf - (2048 + 14336 + 294912);
    const long per_b = 512L * 256 + 64L * 256;   // y1 + out1 floats per sample
    int Bc = (int)(avail / per_b);
    if (Bc > B_) Bc = B_;
    if (Bc < 1) Bc = 1;

    k_repack_w1<<<(512 * 28 + 255) / 256, 256, 0, stream>>>(w1, w1r);
    k_repack_w2<<<294912 / 256, 256, 0, stream>>>(w2, w2r);
    k_mixture<<<B_, 256, 0, stream>>>(x, nw, nb, mix);

    float* out1 = dyn;
    float* y1   = out1 + (size_t)Bc * 16384;

    for (int boff = 0; boff < B_; boff += Bc) {
        int bc = (B_ - boff < Bc) ? (B_ - boff) : Bc;
        k_conv1<<<bc * 8, 256, 0, stream>>>(x, w1r, cb1, y1, boff);
        k_conv2<<<bc * 4, 256, 0, stream>>>(y1, w2r, cb2, mix, out1, boff);
        k_fc<<<bc, 256, 0, stream>>>(out1, fcw, fcb, out, boff);
    }
}

// Round 2
// 298.048 us; speedup vs baseline: 2.1785x; 2.1785x over previous
//
#include <hip/hip_runtime.h>
#include <cstdint>
#include <cstddef>

#define B_ 256
#define C_ 3
#define IW_ 3072
#define L_ 8
#define NN_ 7
#define FCIN_ 16384
#define OUTW_ 10

typedef short short8 __attribute__((ext_vector_type(8)));
typedef float f32x4 __attribute__((ext_vector_type(4)));

__device__ __forceinline__ ushort f2bf(float x) {
    uint u = __float_as_uint(x);
    return (ushort)((u + 0x7fffu + ((u >> 16) & 1u)) >> 16);
}
__device__ __forceinline__ float bf2f(ushort b) { return __uint_as_float(((uint)b) << 16); }

// ---------- repack conv1 weights: [512][3][3][3] -> [512][28] (27 taps + pad) ----------
__global__ void k_repack_w1(const float* __restrict__ w1, float* __restrict__ w1r) {
    int i = blockIdx.x * 256 + threadIdx.x;
    if (i >= 512 * 28) return;
    int o = i / 28, t = i % 28;
    w1r[i] = (t < 27) ? w1[o * 27 + t] : 0.f;
}

// ---------- repack conv2 weights into MFMA frag-linear hi/lo bf16 ----------
// layout: [l8][oh2][icc2][tap9][mt2][lane64][j8]  (ushort)
// oc = oh*32 + mt*16 + (lane&15); ic = icc*32 + (lane>>4)*8 + j
__global__ void k_repack_w2(const float* __restrict__ w2, ushort* __restrict__ w2h,
                            ushort* __restrict__ w2l) {
    int i = blockIdx.x * 256 + threadIdx.x;
    if (i >= 294912) return;
    int j    = i & 7;
    int lane = (i >> 3) & 63;
    int mt   = (i >> 9) & 1;
    int tap  = (i / 1024) % 9;
    int icc  = (i / 9216) & 1;
    int oh   = (i / 18432) & 1;
    int l    = i / 36864;
    int fr = lane & 15, fq = lane >> 4;
    int oc = oh * 32 + mt * 16 + fr;
    int ic = icc * 32 + fq * 8 + j;
    float w = w2[(((size_t)l * 64 + oc) * 64 + ic) * 9 + tap];
    ushort hb = f2bf(w);
    float hf = bf2f(hb);
    w2h[i] = hb;
    w2l[i] = f2bf(w - hf);
}

// ---------- mixture: per-sample soft tree weights [B][8] ----------
__global__ __launch_bounds__(256) void k_mixture(const float* __restrict__ x, const float* __restrict__ nw,
                                                 const float* __restrict__ nb, float* __restrict__ mix) {
    __shared__ float red[4 * NN_];
    __shared__ float bes[NN_];
    int b = blockIdx.x, tid = threadIdx.x;
    const float* xb = x + (size_t)b * IW_;
    float p[NN_];
#pragma unroll
    for (int n = 0; n < NN_; ++n) p[n] = 0.f;
    for (int i = tid; i < IW_; i += 256) {
        float xv = xb[i];
#pragma unroll
        for (int n = 0; n < NN_; ++n) p[n] = fmaf(xv, nw[n * IW_ + i], p[n]);
    }
#pragma unroll
    for (int n = 0; n < NN_; ++n) {
        float v = p[n];
        for (int off = 32; off > 0; off >>= 1) v += __shfl_xor(v, off);
        if ((tid & 63) == 0) red[(tid >> 6) * NN_ + n] = v;
    }
    __syncthreads();
    if (tid < NN_) {
        float s = red[tid] + red[NN_ + tid] + red[2 * NN_ + tid] + red[3 * NN_ + tid] + nb[tid];
        bes[tid] = 1.f / (1.f + expf(-s));
    }
    __syncthreads();
    if (tid < L_) {
        int leaf = tid;
        float b0 = bes[0];
        float t0 = ((leaf >> 2) & 1) ? b0 : 1.f - b0;
        float b1v = bes[1 + ((leaf >> 2) & 1)];
        float t1 = ((leaf >> 1) & 1) ? b1v : 1.f - b1v;
        float b2v = bes[3 + ((leaf >> 1) & 3)];
        float t2 = (leaf & 1) ? b2v : 1.f - b2v;
        mix[b * L_ + leaf] = t0 * t1 * t2;
    }
}

// ---------- conv1 + bias + maxpool2x2 + relu -> y1 hi/lo bf16 [blkLeaf][pos256][ic64] ----------
__global__ __launch_bounds__(256) void k_conv1(const float* __restrict__ x, const float* __restrict__ w1r,
                                               const float* __restrict__ cb1,
                                               ushort* __restrict__ y1h, ushort* __restrict__ y1l, int boff) {
    __shared__ float xl[IW_];       // [3][32][32]
    __shared__ float wl[64 * 28];
    int tid = threadIdx.x;
    int bl = blockIdx.x >> 3, ot = blockIdx.x & 7;
    int b = boff + bl;
    {
        const float4* xs = (const float4*)(x + (size_t)b * IW_);
        for (int i = tid; i < IW_ / 4; i += 256) ((float4*)xl)[i] = xs[i];
        const float4* wsrc = (const float4*)(w1r + ot * 1792);
        for (int i = tid; i < 1792 / 4; i += 256) ((float4*)wl)[i] = wsrc[i];
    }
    __syncthreads();
    int tx = tid & 15, ty = tid >> 4;   // pooled position; pos == tid
    float pch[3][4][4];
#pragma unroll
    for (int c = 0; c < 3; ++c)
#pragma unroll
        for (int r = 0; r < 4; ++r)
#pragma unroll
            for (int s = 0; s < 4; ++s) {
                int gr = 2 * ty - 1 + r, gc = 2 * tx - 1 + s;
                bool ok = ((unsigned)gr < 32u) && ((unsigned)gc < 32u);
                float v = xl[c * 1024 + (ok ? gr * 32 + gc : 0)];
                pch[c][r][s] = ok ? v : 0.f;
            }
    const size_t ybase = ((size_t)(bl * 8 + ot) * 256 + tid) * 64;
#pragma unroll 2
    for (int g = 0; g < 8; ++g) {
        ushort hs[8], ls[8];
#pragma unroll
        for (int e = 0; e < 8; ++e) {
            int oc = g * 8 + e;
            const float* wp = wl + oc * 28;
            float a0 = 0.f, a1 = 0.f, a2 = 0.f, a3 = 0.f;
#pragma unroll
            for (int c = 0; c < 3; ++c)
#pragma unroll
                for (int kh = 0; kh < 3; ++kh)
#pragma unroll
                    for (int kw = 0; kw < 3; ++kw) {
                        float w = wp[c * 9 + kh * 3 + kw];
                        a0 = fmaf(w, pch[c][kh][kw], a0);
                        a1 = fmaf(w, pch[c][kh][kw + 1], a1);
                        a2 = fmaf(w, pch[c][kh + 1][kw], a2);
                        a3 = fmaf(w, pch[c][kh + 1][kw + 1], a3);
                    }
            float v = fmaxf(fmaxf(a0, a1), fmaxf(a2, a3)) + cb1[ot * 64 + oc];
            v = fmaxf(v, 0.f);
            ushort hb = f2bf(v);
            float hf = bf2f(hb);
            hs[e] = hb;
            ls[e] = f2bf(v - hf);
        }
        uint4 ph, pl;
        ph.x = (uint)hs[0] | ((uint)hs[1] << 16); ph.y = (uint)hs[2] | ((uint)hs[3] << 16);
        ph.z = (uint)hs[4] | ((uint)hs[5] << 16); ph.w = (uint)hs[6] | ((uint)hs[7] << 16);
        pl.x = (uint)ls[0] | ((uint)ls[1] << 16); pl.y = (uint)ls[2] | ((uint)ls[3] << 16);
        pl.z = (uint)ls[4] | ((uint)ls[5] << 16); pl.w = (uint)ls[6] | ((uint)ls[7] << 16);
        *(uint4*)(y1h + ybase + g * 8) = ph;
        *(uint4*)(y1l + ybase + g * 8) = pl;
    }
}

// ---------- conv2 via MFMA bf16 3-product split + bias + relu + mixture reduce ----------
// block = (sample bl, oc-half oh). 512 thr = 8 waves; wave w owns ntiles {2w, 2w+1} (pos rows).
// M=32 oc (2 mtiles), N=256 pos (16 ntiles), K per leaf = 64 ic (2 icc chunks of 32).
// Y LDS: [18 rows][18 cols][ic stride 40] bf16, zero borders for halo (stride 40 -> 80B = 5x16B units,
// all 8 bank-groups covered -> ~2-way on ds_read_b128 = free).
#define ICST 40
__global__ __launch_bounds__(512) void k_conv2(const ushort* __restrict__ y1h, const ushort* __restrict__ y1l,
                                               const ushort* __restrict__ w2h, const ushort* __restrict__ w2l,
                                               const float* __restrict__ cb2, const float* __restrict__ mixw,
                                               float* __restrict__ out1, int boff) {
    __shared__ ushort yh[324 * ICST];
    __shared__ ushort yl[324 * ICST];
    int tid = threadIdx.x;
    int bl = blockIdx.x >> 1, oh = blockIdx.x & 1;
    int bg = boff + bl;
    int lane = tid & 63, wid = tid >> 6;
    int fr = lane & 15, fq = lane >> 4;

    // zero both planes (borders stay zero through the whole kernel)
    {
        uint4 z; z.x = z.y = z.z = z.w = 0u;
        for (int i = tid; i < 2 * 1620; i += 512) {
            if (i < 1620) ((uint4*)yh)[i] = z; else ((uint4*)yl)[i - 1620] = z;
        }
    }

    f32x4 acc[2][2], oacc[2][2];
#pragma unroll
    for (int a = 0; a < 2; ++a)
#pragma unroll
        for (int c = 0; c < 2; ++c) { acc[a][c] = (f32x4)0.f; oacc[a][c] = (f32x4)0.f; }

    const size_t ybase_blk = (size_t)bl * 8 * 256 * 64;

    for (int l = 0; l < L_; ++l) {
        for (int icc = 0; icc < 2; ++icc) {
            __syncthreads();
            const ushort* srch = y1h + ybase_blk + (size_t)l * 16384 + icc * 32;
            const ushort* srcl = y1l + ybase_blk + (size_t)l * 16384 + icc * 32;
#pragma unroll
            for (int it = 0; it < 4; ++it) {
                int c4 = it * 512 + tid;           // 0..2047
                int plane = c4 >> 10, rem = c4 & 1023;
                int pos = rem >> 2, kc = rem & 3;
                const ushort* sp = (plane ? srcl : srch) + (size_t)pos * 64 + kc * 8;
                uint4 v = *(const uint4*)sp;
                int r = pos >> 4, c = pos & 15;
                int off = ((r + 1) * 18 + (c + 1)) * ICST + kc * 8;
                *(uint4*)((plane ? yl : yh) + off) = v;
            }
            __syncthreads();
            const ushort* wbh = w2h + (size_t)(((l * 2 + oh) * 2 + icc) * 9) * 1024;
            const ushort* wbl = w2l + (size_t)(((l * 2 + oh) * 2 + icc) * 9) * 1024;
#pragma unroll 3
            for (int tap = 0; tap < 9; ++tap) {
                int kh = tap / 3, kw = tap - kh * 3;
                short8 ah0 = *(const short8*)(wbh + (tap * 2 + 0) * 512 + lane * 8);
                short8 ah1 = *(const short8*)(wbh + (tap * 2 + 1) * 512 + lane * 8);
                short8 al0 = *(const short8*)(wbl + (tap * 2 + 0) * 512 + lane * 8);
                short8 al1 = *(const short8*)(wbl + (tap * 2 + 1) * 512 + lane * 8);
#pragma unroll
                for (int nl = 0; nl < 2; ++nl) {
                    int nt = wid * 2 + nl;
                    int off = ((nt + kh) * 18 + (fr + kw)) * ICST + fq * 8;
                    short8 bh = *(const short8*)(yh + off);
                    short8 bv = *(const short8*)(yl + off);
                    acc[0][nl] = __builtin_amdgcn_mfma_f32_16x16x32_bf16(ah0, bh, acc[0][nl], 0, 0, 0);
                    acc[1][nl] = __builtin_amdgcn_mfma_f32_16x16x32_bf16(ah1, bh, acc[1][nl], 0, 0, 0);
                    acc[0][nl] = __builtin_amdgcn_mfma_f32_16x16x32_bf16(ah0, bv, acc[0][nl], 0, 0, 0);
                    acc[1][nl] = __builtin_amdgcn_mfma_f32_16x16x32_bf16(ah1, bv, acc[1][nl], 0, 0, 0);
                    acc[0][nl] = __builtin_amdgcn_mfma_f32_16x16x32_bf16(al0, bh, acc[0][nl], 0, 0, 0);
                    acc[1][nl] = __builtin_amdgcn_mfma_f32_16x16x32_bf16(al1, bh, acc[1][nl], 0, 0, 0);
                }
            }
        }
        // leaf epilogue: bias + relu + mixture-weighted accumulate
        float m = mixw[(size_t)bg * 8 + l];
#pragma unroll
        for (int mt = 0; mt < 2; ++mt) {
            int ocb = l * 64 + oh * 32 + mt * 16 + fq * 4;
#pragma unroll
            for (int j = 0; j < 4; ++j) {
                float bias = cb2[ocb + j];
#pragma unroll
                for (int nl = 0; nl < 2; ++nl) {
                    float v = fmaxf(acc[mt][nl][j] + bias, 0.f);
                    oacc[mt][nl][j] = fmaf(m, v, oacc[mt][nl][j]);
                    acc[mt][nl][j] = 0.f;
                }
            }
        }
    }
    // store out1 [bl][oc][pos] fp32
#pragma unroll
    for (int mt = 0; mt < 2; ++mt) {
#pragma unroll
        for (int nl = 0; nl < 2; ++nl) {
#pragma unroll
            for (int j = 0; j < 4; ++j) {
                int oc = oh * 32 + mt * 16 + fq * 4 + j;
                int pos = (wid * 2 + nl) * 16 + fr;
                out1[((size_t)bl * 64 + oc) * 256 + pos] = oacc[mt][nl][j];
            }
        }
    }
}

// ---------- fc: [bc][16384] @ [10][16384]^T + b ----------
__global__ __launch_bounds__(256) void k_fc(const float* __restrict__ out1, const float* __restrict__ fcw,
                                            const float* __restrict__ fcb, float* __restrict__ out, int boff) {
    __shared__ float red[4][OUTW_];
    int tid = threadIdx.x;
    int bl = blockIdx.x;
    const float4* flat = (const float4*)(out1 + (size_t)bl * FCIN_);
    float pj[OUTW_];
#pragma unroll
    for (int j = 0; j < OUTW_; ++j) pj[j] = 0.f;
    for (int i = tid; i < FCIN_ / 4; i += 256) {
        float4 v = flat[i];
#pragma unroll
        for (int j = 0; j < OUTW_; ++j) {
            float4 w = ((const float4*)(fcw + (size_t)j * FCIN_))[i];
            pj[j] += v.x * w.x + v.y * w.y + v.z * w.z + v.w * w.w;
        }
    }
#pragma unroll
    for (int j = 0; j < OUTW_; ++j) {
        float v = pj[j];
        for (int off = 32; off > 0; off >>= 1) v += __shfl_xor(v, off);
        if ((tid & 63) == 0) red[tid >> 6][j] = v;
    }
    __syncthreads();
    if (tid < OUTW_) {
        float s = red[0][tid] + red[1][tid] + red[2][tid] + red[3][tid] + fcb[tid];
        out[(size_t)(boff + bl) * OUTW_ + tid] = s;
    }
}

extern "C" void kernel_launch(void* const* d_in, const int* in_sizes, int n_in,
                              void* d_out, int out_size, void* d_ws, size_t ws_size,
                              hipStream_t stream) {
    const float* x   = (const float*)d_in[0];
    const float* nw  = (const float*)d_in[1];
    const float* nb  = (const float*)d_in[2];
    const float* w1  = (const float*)d_in[3];
    const float* cb1 = (const float*)d_in[4];
    const float* w2  = (const float*)d_in[5];
    const float* cb2 = (const float*)d_in[6];
    const float* fcw = (const float*)d_in[7];
    const float* fcb = (const float*)d_in[8];
    float* out = (float*)d_out;

    float*  ws  = (float*)d_ws;
    float*  mix = ws;                       // 2048 f
    float*  w1r = mix + 2048;               // 14336 f
    ushort* w2h = (ushort*)(w1r + 14336);   // 294912 us
    ushort* w2l = w2h + 294912;             // 294912 us

    // fixed bytes: (2048+14336)*4 + 2*294912*2 = 1245184
    const size_t fixed = 1245184;
    long avail = (long)ws_size - (long)fixed;
    const long per_b = 8L * 256 * 64 * 2 * 2 + 16384L * 4;   // y1 hi+lo (bf16) + out1 (f32)
    int Bc = (int)(avail / per_b);
    if (Bc > B_) Bc = B_;
    if (Bc < 1) Bc = 1;

    float*  out1 = (float*)(w2l + 294912);              // Bc*16384 f
    ushort* y1h  = (ushort*)(out1 + (size_t)Bc * 16384); // Bc*131072 us
    ushort* y1l  = y1h + (size_t)Bc * 131072;

    k_repack_w1<<<(512 * 28 + 255) / 256, 256, 0, stream>>>(w1, w1r);
    k_repack_w2<<<294912 / 256, 256, 0, stream>>>(w2, w2h, w2l);
    k_mixture<<<B_, 256, 0, stream>>>(x, nw, nb, mix);

    for (int boff = 0; boff < B_; boff += Bc) {
        int bc = (B_ - boff < Bc) ? (B_ - boff) : Bc;
        k_conv1<<<bc * 8, 256, 0, stream>>>(x, w1r, cb1, y1h, y1l, boff);
        k_conv2<<<bc * 2, 512, 0, stream>>>(y1h, y1l, w2h, w2l, cb2, mix, out1, boff);
        k_fc<<<bc, 256, 0, stream>>>(out1, fcw, fcb, out, boff);
    }
}

// Round 3
// 266.275 us; speedup vs baseline: 2.4384x; 1.1193x over previous
//
#include <hip/hip_runtime.h>
#include <cstdint>
#include <cstddef>

#define B_ 256
#define IW_ 3072
#define L_ 8
#define NN_ 7
#define FCIN_ 16384
#define OUTW_ 10
#define ICST 40   // ushorts per (row,col) cell: 32 ic + 8 pad (16B-aligned, 5 granules -> coprime with 8)

typedef short short8 __attribute__((ext_vector_type(8)));
typedef float f32x4 __attribute__((ext_vector_type(4)));

__device__ __forceinline__ ushort f2bf(float x) {
    uint u = __float_as_uint(x);
    return (ushort)((u + 0x7fffu + ((u >> 16) & 1u)) >> 16);
}
__device__ __forceinline__ float bf2f(ushort b) { return __uint_as_float(((uint)b) << 16); }

// ---------- repack conv1 weights: [512][3][3][3] -> [512][28] (27 taps + pad) ----------
__global__ void k_repack_w1(const float* __restrict__ w1, float* __restrict__ w1r) {
    int i = blockIdx.x * 256 + threadIdx.x;
    if (i >= 512 * 28) return;
    int o = i / 28, t = i % 28;
    w1r[i] = (t < 27) ? w1[o * 27 + t] : 0.f;
}

// ---------- repack conv2 weights into MFMA frag-linear hi/lo bf16 ----------
// layout: [l8][icc2][tap9][mt4][lane64][j8] (ushort);  oc = mt*16 + (lane&15); ic = icc*32 + (lane>>4)*8 + j
__global__ void k_repack_w2(const float* __restrict__ w2, ushort* __restrict__ w2h,
                            ushort* __restrict__ w2l) {
    int i = blockIdx.x * 256 + threadIdx.x;
    if (i >= 294912) return;
    int j    = i & 7;
    int lane = (i >> 3) & 63;
    int mt   = (i >> 9) & 3;
    int tap  = (i >> 11) % 9;
    int icc  = (i / 18432) & 1;
    int l    = i / 36864;
    int fr = lane & 15, fq = lane >> 4;
    int oc = mt * 16 + fr;
    int ic = icc * 32 + fq * 8 + j;
    float w = w2[(((size_t)l * 64 + oc) * 64 + ic) * 9 + tap];
    ushort hb = f2bf(w);
    w2h[i] = hb;
    w2l[i] = f2bf(w - bf2f(hb));
}

// ---------- mixture: per-sample soft tree weights [B][8] ----------
__global__ __launch_bounds__(256) void k_mixture(const float* __restrict__ x, const float* __restrict__ nw,
                                                 const float* __restrict__ nb, float* __restrict__ mix) {
    __shared__ float red[4 * NN_];
    __shared__ float bes[NN_];
    int b = blockIdx.x, tid = threadIdx.x;
    const float* xb = x + (size_t)b * IW_;
    float p[NN_];
#pragma unroll
    for (int n = 0; n < NN_; ++n) p[n] = 0.f;
    for (int i = tid; i < IW_; i += 256) {
        float xv = xb[i];
#pragma unroll
        for (int n = 0; n < NN_; ++n) p[n] = fmaf(xv, nw[n * IW_ + i], p[n]);
    }
#pragma unroll
    for (int n = 0; n < NN_; ++n) {
        float v = p[n];
        for (int off = 32; off > 0; off >>= 1) v += __shfl_xor(v, off);
        if ((tid & 63) == 0) red[(tid >> 6) * NN_ + n] = v;
    }
    __syncthreads();
    if (tid < NN_) {
        float s = red[tid] + red[NN_ + tid] + red[2 * NN_ + tid] + red[3 * NN_ + tid] + nb[tid];
        bes[tid] = 1.f / (1.f + expf(-s));
    }
    __syncthreads();
    if (tid < L_) {
        int leaf = tid;
        float b0 = bes[0];
        float t0 = ((leaf >> 2) & 1) ? b0 : 1.f - b0;
        float b1v = bes[1 + ((leaf >> 2) & 1)];
        float t1 = ((leaf >> 1) & 1) ? b1v : 1.f - b1v;
        float b2v = bes[3 + ((leaf >> 1) & 3)];
        float t2 = (leaf & 1) ? b2v : 1.f - b2v;
        mix[b * L_ + leaf] = t0 * t1 * t2;
    }
}

// ---------- fused conv1(+pool+relu, hi/lo pack) -> LDS -> conv2 MFMA + bias + relu + mixture reduce ----------
// block = sample (512 thr, 8 waves). Leaf x icc step loop:
//   conv1 phase: thread (hh=tid>>8, pos=tid&255) computes 16 chans of the icc-half, packs hi/lo into y LDS tile.
//   conv2 phase: wave tile (4 mtiles x 2 ntiles): zero cross-wave y redundancy; A-frags from global (L2).
// y LDS tile [18][18][ICST] per plane, zero borders = halo. xpad aliases y region (used only in prologue).
__global__ __launch_bounds__(512, 2) void k_fused(const float* __restrict__ x, const float* __restrict__ w1r,
                                                  const float* __restrict__ cb1,
                                                  const ushort* __restrict__ w2h, const ushort* __restrict__ w2l,
                                                  const float* __restrict__ cb2, const float* __restrict__ mixw,
                                                  float* __restrict__ out1, int boff) {
    __shared__ __align__(16) ushort smem[2 * 324 * ICST];   // 51.84 KB: yh | yl (xpad aliases front)
    ushort* yh = smem;
    ushort* yl = smem + 324 * ICST;
    float* xpad = (float*)smem;                              // 3*34*34 floats = 13.9 KB < yh plane

    int tid = threadIdx.x;
    int b = boff + blockIdx.x;
    int lane = tid & 63, wid = tid >> 6;
    int fr = lane & 15, fq = lane >> 4;
    int hh = tid >> 8;          // chan-half within icc chunk
    int p = tid & 255;          // pooled pos
    int pr = p >> 4, pc = p & 15;

    // ---- prologue: xpad (zero + fill) -> patch regs -> zero y planes ----
    for (int i = tid; i < 3 * 34 * 34; i += 512) xpad[i] = 0.f;
    __syncthreads();
    for (int i = tid; i < 3072; i += 512) {
        int ch = i >> 10, rr = (i >> 5) & 31, cc = i & 31;
        xpad[(ch * 34 + rr + 1) * 34 + cc + 1] = x[(size_t)b * IW_ + i];
    }
    __syncthreads();
    float pch[3][4][4];   // step-invariant patch, lives in regs for whole kernel
#pragma unroll
    for (int ch = 0; ch < 3; ++ch)
#pragma unroll
        for (int dr = 0; dr < 4; ++dr) {
            float2 v0 = *(const float2*)&xpad[(ch * 34 + 2 * pr + dr) * 34 + 2 * pc];
            float2 v1 = *(const float2*)&xpad[(ch * 34 + 2 * pr + dr) * 34 + 2 * pc + 2];
            pch[ch][dr][0] = v0.x; pch[ch][dr][1] = v0.y;
            pch[ch][dr][2] = v1.x; pch[ch][dr][3] = v1.y;
        }
    __syncthreads();
    {   // zero y planes (borders stay zero forever)
        uint4 z; z.x = z.y = z.z = z.w = 0u;
        for (int i = tid; i < (2 * 324 * ICST) / 8; i += 512) ((uint4*)smem)[i] = z;
    }
    __syncthreads();

    f32x4 acc[4][2], oacc[4][2];
#pragma unroll
    for (int mt = 0; mt < 4; ++mt)
#pragma unroll
        for (int nl = 0; nl < 2; ++nl) { acc[mt][nl] = (f32x4)0.f; oacc[mt][nl] = (f32x4)0.f; }

    const int yoff_w = ((pr + 1) * 18 + (pc + 1)) * ICST + hh * 16;

    for (int s = 0; s < 16; ++s) {
        int l = s >> 1, icc = s & 1;
        // ---- conv1 phase: 16 chans ----
        const float* wbase = w1r + (size_t)(l * 64 + icc * 32 + hh * 16) * 28;
        const float* bbase = cb1 + l * 64 + icc * 32 + hh * 16;
        uint hp[8], lp[8];
#pragma unroll
        for (int q = 0; q < 8; ++q) { hp[q] = 0u; lp[q] = 0u; }
#pragma unroll 4
        for (int e = 0; e < 16; ++e) {
            float wq[28];
#pragma unroll
            for (int q = 0; q < 7; ++q) *(float4*)&wq[q * 4] = ((const float4*)(wbase + e * 28))[q];
            float a0 = 0.f, a1 = 0.f, a2 = 0.f, a3 = 0.f;
#pragma unroll
            for (int ch = 0; ch < 3; ++ch)
#pragma unroll
                for (int kh = 0; kh < 3; ++kh)
#pragma unroll
                    for (int kw = 0; kw < 3; ++kw) {
                        float w = wq[ch * 9 + kh * 3 + kw];
                        a0 = fmaf(w, pch[ch][kh][kw], a0);
                        a1 = fmaf(w, pch[ch][kh][kw + 1], a1);
                        a2 = fmaf(w, pch[ch][kh + 1][kw], a2);
                        a3 = fmaf(w, pch[ch][kh + 1][kw + 1], a3);
                    }
            float v = fmaxf(fmaxf(a0, a1), fmaxf(a2, a3)) + bbase[e];
            v = fmaxf(v, 0.f);
            ushort hb = f2bf(v);
            ushort lb = f2bf(v - bf2f(hb));
            hp[e >> 1] |= (uint)hb << (16 * (e & 1));
            lp[e >> 1] |= (uint)lb << (16 * (e & 1));
        }
        {
            uint4 H0, H1, L0v, L1v;
            H0.x = hp[0]; H0.y = hp[1]; H0.z = hp[2]; H0.w = hp[3];
            H1.x = hp[4]; H1.y = hp[5]; H1.z = hp[6]; H1.w = hp[7];
            L0v.x = lp[0]; L0v.y = lp[1]; L0v.z = lp[2]; L0v.w = lp[3];
            L1v.x = lp[4]; L1v.y = lp[5]; L1v.z = lp[6]; L1v.w = lp[7];
            *(uint4*)&yh[yoff_w] = H0; *(uint4*)&yh[yoff_w + 8] = H1;
            *(uint4*)&yl[yoff_w] = L0v; *(uint4*)&yl[yoff_w + 8] = L1v;
        }
        __syncthreads();

        // ---- conv2 MFMA phase: 9 taps, wave tile (4mt x 2nl) ----
        const ushort* wa_h = w2h + (size_t)((l * 2 + icc) * 9) * 4 * 512;
        const ushort* wa_l = w2l + (size_t)((l * 2 + icc) * 9) * 4 * 512;
#pragma unroll
        for (int kh = 0; kh < 3; ++kh)
#pragma unroll
            for (int kw = 0; kw < 3; ++kw) {
                int tap = kh * 3 + kw;
                short8 ah[4], al[4];
#pragma unroll
                for (int mt = 0; mt < 4; ++mt) {
                    ah[mt] = *(const short8*)(wa_h + ((size_t)(tap * 4 + mt) * 64 + lane) * 8);
                    al[mt] = *(const short8*)(wa_l + ((size_t)(tap * 4 + mt) * 64 + lane) * 8);
                }
#pragma unroll
                for (int nl = 0; nl < 2; ++nl) {
                    int off = (((wid * 2 + nl) + kh) * 18 + (fr + kw)) * ICST + fq * 8;
                    short8 bh = *(const short8*)(yh + off);
                    short8 bv = *(const short8*)(yl + off);
#pragma unroll
                    for (int mt = 0; mt < 4; ++mt) {
                        acc[mt][nl] = __builtin_amdgcn_mfma_f32_16x16x32_bf16(ah[mt], bh, acc[mt][nl], 0, 0, 0);
                        acc[mt][nl] = __builtin_amdgcn_mfma_f32_16x16x32_bf16(ah[mt], bv, acc[mt][nl], 0, 0, 0);
                        acc[mt][nl] = __builtin_amdgcn_mfma_f32_16x16x32_bf16(al[mt], bh, acc[mt][nl], 0, 0, 0);
                    }
                }
            }
        if (icc) {  // leaf epilogue: bias + relu + mixture accumulate
            float m = mixw[(size_t)b * 8 + l];
#pragma unroll
            for (int mt = 0; mt < 4; ++mt)
#pragma unroll
                for (int j = 0; j < 4; ++j) {
                    float bias = cb2[l * 64 + mt * 16 + fq * 4 + j];
#pragma unroll
                    for (int nl = 0; nl < 2; ++nl) {
                        float v = fmaxf(acc[mt][nl][j] + bias, 0.f);
                        oacc[mt][nl][j] = fmaf(m, v, oacc[mt][nl][j]);
                        acc[mt][nl][j] = 0.f;
                    }
                }
        }
        __syncthreads();
    }

    // ---- store out1 [b][64 oc][256 pos] fp32 ----
#pragma unroll
    for (int mt = 0; mt < 4; ++mt)
#pragma unroll
        for (int nl = 0; nl < 2; ++nl)
#pragma unroll
            for (int j = 0; j < 4; ++j) {
                int oc = mt * 16 + fq * 4 + j;
                int pos = (wid * 2 + nl) * 16 + fr;
                out1[((size_t)blockIdx.x * 64 + oc) * 256 + pos] = oacc[mt][nl][j];
            }
}

// ---------- fc: [bc][16384] @ [10][16384]^T + b ----------
__global__ __launch_bounds__(256) void k_fc(const float* __restrict__ out1, const float* __restrict__ fcw,
                                            const float* __restrict__ fcb, float* __restrict__ out, int boff) {
    __shared__ float red[4][OUTW_];
    int tid = threadIdx.x;
    int bl = blockIdx.x;
    const float4* flat = (const float4*)(out1 + (size_t)bl * FCIN_);
    float pj[OUTW_];
#pragma unroll
    for (int j = 0; j < OUTW_; ++j) pj[j] = 0.f;
    for (int i = tid; i < FCIN_ / 4; i += 256) {
        float4 v = flat[i];
#pragma unroll
        for (int j = 0; j < OUTW_; ++j) {
            float4 w = ((const float4*)(fcw + (size_t)j * FCIN_))[i];
            pj[j] += v.x * w.x + v.y * w.y + v.z * w.z + v.w * w.w;
        }
    }
#pragma unroll
    for (int j = 0; j < OUTW_; ++j) {
        float v = pj[j];
        for (int off = 32; off > 0; off >>= 1) v += __shfl_xor(v, off);
        if ((tid & 63) == 0) red[tid >> 6][j] = v;
    }
    __syncthreads();
    if (tid < OUTW_) {
        float s = red[0][tid] + red[1][tid] + red[2][tid] + red[3][tid] + fcb[tid];
        out[(size_t)(boff + bl) * OUTW_ + tid] = s;
    }
}

extern "C" void kernel_launch(void* const* d_in, const int* in_sizes, int n_in,
                              void* d_out, int out_size, void* d_ws, size_t ws_size,
                              hipStream_t stream) {
    const float* x   = (const float*)d_in[0];
    const float* nw  = (const float*)d_in[1];
    const float* nb  = (const float*)d_in[2];
    const float* w1  = (const float*)d_in[3];
    const float* cb1 = (const float*)d_in[4];
    const float* w2  = (const float*)d_in[5];
    const float* cb2 = (const float*)d_in[6];
    const float* fcw = (const float*)d_in[7];
    const float* fcb = (const float*)d_in[8];
    float* out = (float*)d_out;

    float*  ws  = (float*)d_ws;
    float*  mix = ws;                       // 2048 f
    float*  w1r = mix + 2048;               // 14336 f
    ushort* w2h = (ushort*)(w1r + 14336);   // 294912 us
    ushort* w2l = w2h + 294912;             // 294912 us
    float*  out1 = (float*)(w2l + 294912);  // Bc * 16384 f

    // fixed bytes: (2048+14336)*4 + 2*294912*2 = 1245184; out1 per sample = 65536 B
    long avail = (long)ws_size - 1245184L;
    int Bc = (int)(avail / 65536L);
    if (Bc > B_) Bc = B_;
    if (Bc < 1) Bc = 1;

    k_repack_w1<<<(512 * 28 + 255) / 256, 256, 0, stream>>>(w1, w1r);
    k_repack_w2<<<294912 / 256, 256, 0, stream>>>(w2, w2h, w2l);
    k_mixture<<<B_, 256, 0, stream>>>(x, nw, nb, mix);

    for (int boff = 0; boff < B_; boff += Bc) {
        int bc = (B_ - boff < Bc) ? (B_ - boff) : Bc;
        k_fused<<<bc, 512, 0, stream>>>(x, w1r, cb1, w2h, w2l, cb2, mix, out1, boff);
        k_fc<<<bc, 256, 0, stream>>>(out1, fcw, fcb, out, boff);
    }
}